// Round 8
// baseline (324.972 us; speedup 1.0000x reference)
//
#include <hip/hip_runtime.h>
#include <hip/hip_bf16.h>
#include <stdint.h>

// Problem constants (FC_Caps): B=32, I=1024, O=64, D_out=32, D_in=16
#define B_  32
#define I_  1024
#define O_  64
#define D_  32
#define N_  16
#define OD_ 2048   // O_*D_

// ---------- bf16 helpers (bit-exact RNE pack, shift unpack) ----------
__device__ __forceinline__ uint32_t f2bf1(float f) {
  uint32_t u = __float_as_uint(f);
  return (u + 0x7fffu + ((u >> 16) & 1u)) >> 16;
}
__device__ __forceinline__ uint32_t pack2(float a, float b) {
  return f2bf1(a) | (f2bf1(b) << 16);
}
__device__ __forceinline__ float bflo(uint32_t v) { return __uint_as_float(v << 16); }
__device__ __forceinline__ float bfhi(uint32_t v) { return __uint_as_float(v & 0xffff0000u); }
__device__ __forceinline__ void unpack8(uint4 r, float* u) {
  u[0] = bflo(r.x); u[1] = bfhi(r.x);
  u[2] = bflo(r.y); u[3] = bfhi(r.y);
  u[4] = bflo(r.z); u[5] = bfhi(r.z);
  u[6] = bflo(r.w); u[7] = bfhi(r.w);
}

// ---------- K1: u_hat = W·x (bf16 out) FUSED with iter-0 partial sum over i ----------
// Block = (ichunk of 8 i's, od-eighth). Thread owns ONE od row (64 B = one
// cache line per lane, fully consumed; W read exactly once chip-wide).
// While the fp32 'a' is still in registers, accumulate sum_acc[b] += a —
// this replaces the entire k_sum0 pass (128 MB re-read eliminated).
__global__ __launch_bounds__(256) void k_einsum_fused(const float* __restrict__ x,
                                                      const float* __restrict__ W,
                                                      uint16_t* __restrict__ uhat,
                                                      uint16_t* __restrict__ parte) {
  const int e  = blockIdx.x & 7;        // od-eighth
  const int ic = blockIdx.x >> 3;       // i-chunk 0..127
  const int t  = threadIdx.x;
  const int od = e * 256 + t;
  const int i0 = ic * 8;
  __shared__ float xs[8 * 32 * 16];     // [ii][b][n], 16 KB
  for (int idx = t; idx < 8 * 32 * 16; idx += 256) {
    int ii = idx >> 9, rem = idx & 511, bb = rem >> 4, n = rem & 15;
    xs[idx] = x[(size_t)bb * (I_ * N_) + (size_t)(i0 + ii) * N_ + n];
  }
  __syncthreads();
  float sum_acc[32];
  #pragma unroll
  for (int bb = 0; bb < 32; ++bb) sum_acc[bb] = 0.f;
  for (int ii = 0; ii < 8; ++ii) {
    const int i = i0 + ii;
    float w[16];
    {
      const float4* Wr = (const float4*)(W + (size_t)i * (OD_ * N_) + (size_t)od * N_);
      #pragma unroll
      for (int qq = 0; qq < 4; ++qq) {
        float4 f = Wr[qq];
        w[qq * 4 + 0] = f.x; w[qq * 4 + 1] = f.y;
        w[qq * 4 + 2] = f.z; w[qq * 4 + 3] = f.w;
      }
    }
    const float* xb = xs + ii * 512;
    #pragma unroll 4
    for (int bb = 0; bb < 32; ++bb) {
      float4 x0 = ((const float4*)(xb + bb * 16))[0];
      float4 x1 = ((const float4*)(xb + bb * 16))[1];
      float4 x2 = ((const float4*)(xb + bb * 16))[2];
      float4 x3 = ((const float4*)(xb + bb * 16))[3];
      float a = 0.f;
      a = fmaf(w[0],  x0.x, a); a = fmaf(w[1],  x0.y, a);
      a = fmaf(w[2],  x0.z, a); a = fmaf(w[3],  x0.w, a);
      a = fmaf(w[4],  x1.x, a); a = fmaf(w[5],  x1.y, a);
      a = fmaf(w[6],  x1.z, a); a = fmaf(w[7],  x1.w, a);
      a = fmaf(w[8],  x2.x, a); a = fmaf(w[9],  x2.y, a);
      a = fmaf(w[10], x2.z, a); a = fmaf(w[11], x2.w, a);
      a = fmaf(w[12], x3.x, a); a = fmaf(w[13], x3.y, a);
      a = fmaf(w[14], x3.z, a); a = fmaf(w[15], x3.w, a);
      uhat[((size_t)bb * I_ + i) * OD_ + od] = (uint16_t)f2bf1(a);
      sum_acc[bb] += a;
    }
  }
  #pragma unroll
  for (int bb = 0; bb < 32; ++bb)
    parte[((size_t)bb * 128 + ic) * OD_ + od] = (uint16_t)f2bf1(sum_acc[bb]);
}

// ---------- squash: reduce nchunk bf16 partials, scale, (+bias), squash over d ----------
__global__ __launch_bounds__(256) void k_squash(const uint16_t* __restrict__ part,
                                                const float* __restrict__ bias,
                                                float* __restrict__ vout,
                                                float scale, int addBias, int nchunk) {
  const int lane = threadIdx.x & 63;
  const int row = blockIdx.x * 4 + (threadIdx.x >> 6);  // b=row>>6, o=row&63
  const int b = row >> 6, o = row & 63;
  const int d = lane & 31;
  const uint16_t* p = part + (size_t)b * ((size_t)nchunk * OD_) + (size_t)o * 32 + d;
  float s = 0.f;
  const int half = nchunk >> 1;
  const int c0 = (lane >> 5) * half;   // half-waves split the chunks
  for (int c = c0; c < c0 + half; ++c)
    s += __uint_as_float(((uint32_t)p[(size_t)c * OD_]) << 16);
  s += __shfl_xor(s, 32);
  s *= scale;
  if (addBias) s += bias[o * 32 + d];
  float dot = s * s;
  #pragma unroll
  for (int off = 1; off <= 16; off <<= 1) dot += __shfl_xor(dot, off);
  float sc = dot / (1.f + dot) / sqrtf(dot + 1e-8f);
  if (lane < 32) vout[(size_t)row * 32 + d] = s * sc;
}

// ---------- routing pass (iters 1 and 2), lane = o, minimal registers ----------
// (frozen from R7 — no-spill, ~38 us/pass)
__global__ __launch_bounds__(256) void k_route(const uint4* __restrict__ uhat,
                                               const float* __restrict__ vprev,
                                               float* __restrict__ bij,
                                               uint4* __restrict__ part,
                                               int secondIter) {
  const int b = blockIdx.x >> 5, chunk = blockIdx.x & 31;
  const int t = threadIdx.x;
  const int w = t >> 6, lane = t & 63;   // lane = o
  __shared__ float red[4][64][32];       // 32 KB, swizzled [w][o][(d+o)&31]
  uint32_t vp[16];
  {
    const float4* vpt = (const float4*)(vprev + ((size_t)b * 64 + lane) * 32);
    #pragma unroll
    for (int q = 0; q < 8; ++q) {
      float4 f = vpt[q];
      vp[2 * q]     = pack2(f.x, f.y);
      vp[2 * q + 1] = pack2(f.z, f.w);
    }
  }
  float s_acc[32];
  #pragma unroll
  for (int d = 0; d < 32; ++d) s_acc[d] = 0.f;
  const int i0 = chunk * 32 + w * 8;
  const uint4* ub = uhat + ((size_t)b * I_ + i0) * 256 + (size_t)lane * 4;
  for (int r = 0; r < 8; ++r) {
    const uint4* uc = ub + (size_t)r * 256;
    uint4 c0 = uc[0], c1 = uc[1], c2 = uc[2], c3 = uc[3];
    float a = 0.f;
    {
      float u8[8];
      unpack8(c0, u8);
      #pragma unroll
      for (int p = 0; p < 4; ++p) {
        uint32_t vv = vp[p];
        a = fmaf(u8[2 * p], bflo(vv), a);
        a = fmaf(u8[2 * p + 1], bfhi(vv), a);
      }
      unpack8(c1, u8);
      #pragma unroll
      for (int p = 0; p < 4; ++p) {
        uint32_t vv = vp[4 + p];
        a = fmaf(u8[2 * p], bflo(vv), a);
        a = fmaf(u8[2 * p + 1], bfhi(vv), a);
      }
      unpack8(c2, u8);
      #pragma unroll
      for (int p = 0; p < 4; ++p) {
        uint32_t vv = vp[8 + p];
        a = fmaf(u8[2 * p], bflo(vv), a);
        a = fmaf(u8[2 * p + 1], bfhi(vv), a);
      }
      unpack8(c3, u8);
      #pragma unroll
      for (int p = 0; p < 4; ++p) {
        uint32_t vv = vp[12 + p];
        a = fmaf(u8[2 * p], bflo(vv), a);
        a = fmaf(u8[2 * p + 1], bfhi(vv), a);
      }
    }
    const int i = i0 + r;
    const size_t bidx = ((size_t)b * I_ + i) * 64 + lane;
    float bn = a;
    if (secondIter) bn += bij[bidx];
    else            bij[bidx] = bn;
    float m = bn;
    #pragma unroll
    for (int off = 1; off <= 32; off <<= 1) m = fmaxf(m, __shfl_xor(m, off));
    float ev = __expf(bn - m);
    float sm = ev;
    #pragma unroll
    for (int off = 1; off <= 32; off <<= 1) sm += __shfl_xor(sm, off);
    const float c = ev / sm;
    {
      float u8[8];
      unpack8(c0, u8);
      #pragma unroll
      for (int j = 0; j < 8; ++j) s_acc[j] = fmaf(c, u8[j], s_acc[j]);
      unpack8(c1, u8);
      #pragma unroll
      for (int j = 0; j < 8; ++j) s_acc[8 + j] = fmaf(c, u8[j], s_acc[8 + j]);
      unpack8(c2, u8);
      #pragma unroll
      for (int j = 0; j < 8; ++j) s_acc[16 + j] = fmaf(c, u8[j], s_acc[16 + j]);
      unpack8(c3, u8);
      #pragma unroll
      for (int j = 0; j < 8; ++j) s_acc[24 + j] = fmaf(c, u8[j], s_acc[24 + j]);
    }
  }
  #pragma unroll
  for (int d = 0; d < 32; ++d) red[w][lane][(d + lane) & 31] = s_acc[d];
  __syncthreads();
  {
    const int o = t >> 2, db = (t & 3) * 8;
    float sum[8];
    #pragma unroll
    for (int j = 0; j < 8; ++j) {
      const int sw = (db + j + o) & 31;
      sum[j] = red[0][o][sw] + red[1][o][sw] + red[2][o][sw] + red[3][o][sw];
    }
    part[(((size_t)b * 32 + chunk) * OD_ + (size_t)t * 8) >> 3] =
        make_uint4(pack2(sum[0], sum[1]), pack2(sum[2], sum[3]),
                   pack2(sum[4], sum[5]), pack2(sum[6], sum[7]));
  }
}

extern "C" void kernel_launch(void* const* d_in, const int* in_sizes, int n_in,
                              void* d_out, int out_size, void* d_ws, size_t ws_size,
                              hipStream_t stream) {
  const float* x    = (const float*)d_in[0];  // [32,1024,16]
  const float* W    = (const float*)d_in[1];  // [1,1024,64,32,16]
  const float* bias = (const float*)d_in[2];  // [1,1,64,32]
  float* out = (float*)d_out;                 // [32,64,32]

  char* ws = (char*)d_ws;
  uint16_t* uhat1 = (uint16_t*)ws;                            // 128 MB bf16 u_hat
  uint4*    uhat4 = (uint4*)ws;
  float* bij   = (float*)(ws + 134217728ull);                 // 8 MB  b_ij[b,i,o]
  // part_e: [b][128][od] bf16 (16 MB), aliased by part_r [b][32][od] (4 MB) —
  // part_e fully consumed by the first squash before route writes part_r.
  uint16_t* parte16 = (uint16_t*)(ws + 134217728ull + 8388608ull);
  uint4*    partr4  = (uint4*)(ws + 134217728ull + 8388608ull);
  uint16_t* partr16 = (uint16_t*)partr4;
  float* vbuf = (float*)(ws + 134217728ull + 8388608ull + 16777216ull);  // 256 KB

  k_einsum_fused<<<dim3(1024), dim3(256), 0, stream>>>(x, W, uhat1, parte16);
  // iter 0: uniform c = 1/64 — partial sums already produced by the fused einsum
  k_squash<<<dim3(512), dim3(256), 0, stream>>>(parte16, bias, vbuf, 1.f / 64.f, 0, 128);
  // iter 1
  k_route <<<dim3(1024), dim3(256), 0, stream>>>(uhat4, vbuf, bij, partr4, 0);
  k_squash<<<dim3(512), dim3(256), 0, stream>>>(partr16, bias, vbuf, 1.f, 0, 32);
  // iter 2 (last): + bias, output
  k_route <<<dim3(1024), dim3(256), 0, stream>>>(uhat4, vbuf, bij, partr4, 1);
  k_squash<<<dim3(512), dim3(256), 0, stream>>>(partr16, bias, out, 1.f, 1, 32);
}